// Round 6
// baseline (173.303 us; speedup 1.0000x reference)
//
#include <hip/hip_runtime.h>
#include <hip/hip_bf16.h>

// SlotAttention: B=128, N=8192, S=4, D=32, ITERS=3.  Output dtype: float32.
//
// 4 launches:
//   pass<0>: read x fp32, write y = LN(x) as bf16, accumulate it-0 partials.
//            Prologue (redundant per block): init slots0, qt0.
//   pass<1>: read y bf16, accumulate it-1 partials. Prologue: update -> slots1, qt1.
//   pass<2>: read y bf16, accumulate it-2 partials. Prologue: update -> slots2, qt2.
//   final  : update -> slots3 -> out (fp32).
// Algebra: k,v never materialized; logit_s = qt_s . y_n; u = sum w_n y_n.
// bf16 y is safe: logits span only ~±1.3 (flat softmax, N_eff ~ thousands),
// so rounding errors average down; margin to threshold is ~60x.

#define Bn 128
#define Nn 8192
#define Sn 4
#define Dn 32
#define SCALE 0.17677669529663687f   // D^-0.5
#define RENORM (1.0f / (1.0f + (float)Nn * 1e-8f))

#define Cn 16                  // chunks per batch
#define RPB (Nn / Cn)          // 512 rows per block
#define PT 256                 // pass threads (4 waves)
#define RSTEP (PT / 4)         // 64 rows per step (4 lanes per row)
#define NSTEP (RPB / RSTEP)    // 8 steps

#define WS_REQ ((size_t)(3 * Bn * Sn * Dn + 3 * Bn * Cn * Sn * Dn + 3 * Bn * Cn * Sn) * 4 \
                + (size_t)Bn * Nn * Dn * 2)

__device__ __forceinline__ float sigmoidf_(float v) { return 1.0f / (1.0f + __expf(-v)); }
__device__ __forceinline__ unsigned f2bf_rne(float f) {
    unsigned u = __float_as_uint(f);
    u += 0x7fffu + ((u >> 16) & 1u);
    return u >> 16;
}
__device__ __forceinline__ float bflo2f(unsigned u) { return __uint_as_float(u << 16); }
__device__ __forceinline__ float bfhi2f(unsigned u) { return __uint_as_float(u & 0xffff0000u); }

// ---------------------------------------------------------------------------
// chain: compute slots_i (KIND=0: init from noise; KIND=1: GRU/MLP update from
// partials) and optionally qt_i into qt_sh. Call from ALL threads (syncs are
// uniform); threads >=128 idle through it. `store` != nullptr -> persist sfin.
// ---------------------------------------------------------------------------
template<int KIND, int WANT_QT>
__device__ __forceinline__ void chain_fn(
    int b, int tid,
    const float* __restrict__ pa_prev, const float* __restrict__ ps_prev,
    const float* __restrict__ slots_prev,
    const float* __restrict__ noise, const float* __restrict__ mu,
    const float* __restrict__ logsig,
    const float* __restrict__ Wv,
    const float* __restrict__ Wih, const float* __restrict__ Whh,
    const float* __restrict__ bih, const float* __restrict__ bhh,
    const float* __restrict__ W1, const float* __restrict__ b1v,
    const float* __restrict__ W2, const float* __restrict__ b2v,
    const float* __restrict__ lns_g, const float* __restrict__ lns_b,
    const float* __restrict__ lnff_g, const float* __restrict__ lnff_b,
    const float* __restrict__ Wq, const float* __restrict__ Wk,
    float (*qt_sh)[Dn], float (*ta)[Dn], float (*tb)[Dn],
    float* __restrict__ store)
{
    const int s = (tid >> 5) & 3, d = tid & 31;
    const bool act = tid < 128;
    float sfin = 0.f;

    if constexpr (KIND == 0) {
        if (act)
            sfin = mu[d] + noise[(b * Sn + s) * Dn + d] * __expf(logsig[d]);
    } else {
        float sv_c = 0.f, lnffv = 0.f;
        if (act) {
            float u = 0.f, PS = 0.f;
            #pragma unroll
            for (int c = 0; c < Cn; ++c) {
                u  += pa_prev[(((size_t)b * Cn + c) * Sn + s) * Dn + d];
                PS += ps_prev[((size_t)b * Cn + c) * Sn + s];
            }
            ta[s][d] = (u / PS) * RENORM;                 // ubar
            tb[s][d] = slots_prev[(b * Sn + s) * Dn + d]; // sold
        }
        __syncthreads();
        float updv = 0.f;
        if (act) {
            #pragma unroll 8
            for (int j = 0; j < 32; ++j) updv = fmaf(Wv[d * 32 + j], ta[s][j], updv);
        }
        __syncthreads();
        if (act) ta[s][d] = updv;                        // upd
        __syncthreads();
        if (act) {
            float gi[3], gh[3];
            #pragma unroll
            for (int g3 = 0; g3 < 3; ++g3) {
                const int row = g3 * 32 + d;
                float a1 = bih[row], a2 = bhh[row];
                #pragma unroll 8
                for (int j = 0; j < 32; ++j) {
                    a1 = fmaf(Wih[row * 32 + j], ta[s][j], a1);
                    a2 = fmaf(Whh[row * 32 + j], tb[s][j], a2);
                }
                gi[g3] = a1; gh[g3] = a2;
            }
            float r  = sigmoidf_(gi[0] + gh[0]);
            float z  = sigmoidf_(gi[1] + gh[1]);
            float nn = tanhf(gi[2] + r * gh[2]);
            sv_c = (1.0f - z) * nn + z * tb[s][d];
            float sx = sv_c, sxx = sv_c * sv_c;
            #pragma unroll
            for (int m = 1; m <= 16; m <<= 1) { sx += __shfl_xor(sx, m); sxx += __shfl_xor(sxx, m); }
            float mean = sx * (1.0f / 32.0f);
            float var  = sxx * (1.0f / 32.0f) - mean * mean;
            lnffv = (sv_c - mean) * rsqrtf(var + 1e-5f) * lnff_g[d] + lnff_b[d];
        }
        __syncthreads();
        if (act) ta[s][d] = lnffv;
        __syncthreads();
        if (act) {
            float h = b1v[d];
            #pragma unroll 8
            for (int j = 0; j < 32; ++j) h = fmaf(W1[d * 32 + j], ta[s][j], h);
            tb[s][d] = fmaxf(h, 0.f);
        }
        __syncthreads();
        if (act) {
            float o = b2v[d];
            #pragma unroll 8
            for (int j = 0; j < 32; ++j) o = fmaf(W2[d * 32 + j], tb[s][j], o);
            sfin = sv_c + o;
        }
    }

    if (act && store) store[(b * Sn + s) * Dn + d] = sfin;

    if constexpr (WANT_QT) {
        float lnsv = 0.f;
        if (act) {
            float sx = sfin, sxx = sfin * sfin;
            #pragma unroll
            for (int m = 1; m <= 16; m <<= 1) { sx += __shfl_xor(sx, m); sxx += __shfl_xor(sxx, m); }
            float mean = sx * (1.0f / 32.0f);
            float var  = sxx * (1.0f / 32.0f) - mean * mean;
            lnsv = (sfin - mean) * rsqrtf(var + 1e-5f) * lns_g[d] + lns_b[d];
        }
        __syncthreads();
        if (act) ta[s][d] = lnsv;
        __syncthreads();
        if (act) {
            float q = 0.f;
            #pragma unroll 8
            for (int j = 0; j < 32; ++j) q = fmaf(Wq[d * 32 + j], ta[s][j], q);
            tb[s][d] = q;
        }
        __syncthreads();
        if (act) {
            float qv = 0.f;
            #pragma unroll 8
            for (int i = 0; i < 32; ++i) qv = fmaf(tb[s][i], Wk[i * 32 + d], qv);
            qt_sh[s][d] = qv * SCALE;
        }
        __syncthreads();
    }
}

// ---------------------------------------------------------------------------
// pass kernel: prologue chain (init or update) then stream rows.
// IT==0: read x fp32, write y bf16.  IT>0: read y bf16.
// ---------------------------------------------------------------------------
template<int IT>
__global__ __launch_bounds__(PT)
void pass_k(const float* __restrict__ x, unsigned short* __restrict__ y,
            const float* __restrict__ noise, const float* __restrict__ mu,
            const float* __restrict__ logsig,
            const float* __restrict__ Wq, const float* __restrict__ Wk,
            const float* __restrict__ Wv,
            const float* __restrict__ Wih, const float* __restrict__ Whh,
            const float* __restrict__ bih, const float* __restrict__ bhh,
            const float* __restrict__ W1, const float* __restrict__ b1v,
            const float* __restrict__ W2, const float* __restrict__ b2v,
            const float* __restrict__ lnx_g, const float* __restrict__ lnx_b,
            const float* __restrict__ lns_g, const float* __restrict__ lns_b,
            const float* __restrict__ lnff_g, const float* __restrict__ lnff_b,
            const float* __restrict__ slots_prev, float* __restrict__ slots_cur,
            const float* __restrict__ pa_prev, const float* __restrict__ ps_prev,
            float* __restrict__ pa_cur, float* __restrict__ ps_cur)
{
    const int c = blockIdx.x, b = blockIdx.y, tid = threadIdx.x;
    __shared__ float qt_sh[Sn][Dn], ta[Sn][Dn], tb[Sn][Dn];
    __shared__ float ls_pa[4][Sn][Dn];
    __shared__ float ls_ps[4][Sn];

    chain_fn<(IT == 0 ? 0 : 1), 1>(b, tid, pa_prev, ps_prev, slots_prev,
        noise, mu, logsig, Wv, Wih, Whh, bih, bhh, W1, b1v, W2, b2v,
        lns_g, lns_b, lnff_g, lnff_b, Wq, Wk,
        qt_sh, ta, tb, (c == 0) ? slots_cur : nullptr);

    const int sub = tid & 3, col0 = sub * 8, rg = tid >> 2;
    float pa[4][8];
    float ps[4] = {0.f, 0.f, 0.f, 0.f};
    #pragma unroll
    for (int s = 0; s < 4; ++s)
        #pragma unroll
        for (int k = 0; k < 8; ++k) pa[s][k] = 0.f;

    if constexpr (IT == 0) {
        float g_r[8], e_r[8];
        #pragma unroll
        for (int k = 0; k < 8; ++k) { g_r[k] = lnx_g[col0 + k]; e_r[k] = lnx_b[col0 + k]; }
        float qg[4][8], qgs[4], qe[4];
        #pragma unroll
        for (int s = 0; s < 4; ++s) {
            float sg = 0.f, se = 0.f;
            #pragma unroll
            for (int k = 0; k < 8; ++k) {
                float q = qt_sh[s][col0 + k];
                qg[s][k] = q * g_r[k];
                sg += qg[s][k];
                se = fmaf(q, e_r[k], se);
            }
            sg += __shfl_xor(sg, 1); sg += __shfl_xor(sg, 2);
            se += __shfl_xor(se, 1); se += __shfl_xor(se, 2);
            qgs[s] = sg; qe[s] = se;
        }

        const float* xb = x + ((size_t)b * Nn + (size_t)c * RPB) * Dn;
        unsigned short* yb = y + ((size_t)b * Nn + (size_t)c * RPB) * Dn;
        const float* p0 = xb + (size_t)rg * Dn + col0;
        float4 v0 = *(const float4*)(p0);
        float4 v1 = *(const float4*)(p0 + 4);

        for (int t = 0; t < NSTEP; ++t) {
            const int tn = (t + 1 < NSTEP) ? t + 1 : t;
            const float* pn = xb + (size_t)(tn * RSTEP + rg) * Dn + col0;
            float4 n0 = *(const float4*)(pn);
            float4 n1 = *(const float4*)(pn + 4);

            float xv[8] = {v0.x, v0.y, v0.z, v0.w, v1.x, v1.y, v1.z, v1.w};
            float sx = 0.f, sxx = 0.f, ds[4] = {0.f, 0.f, 0.f, 0.f};
            #pragma unroll
            for (int k = 0; k < 8; ++k) {
                sx += xv[k];
                sxx = fmaf(xv[k], xv[k], sxx);
                #pragma unroll
                for (int s = 0; s < 4; ++s) ds[s] = fmaf(xv[k], qg[s][k], ds[s]);
            }
            sx += __shfl_xor(sx, 1); sxx += __shfl_xor(sxx, 1);
            #pragma unroll
            for (int s = 0; s < 4; ++s) ds[s] += __shfl_xor(ds[s], 1);
            sx += __shfl_xor(sx, 2); sxx += __shfl_xor(sxx, 2);
            #pragma unroll
            for (int s = 0; s < 4; ++s) ds[s] += __shfl_xor(ds[s], 2);

            float mean = sx * (1.0f / 32.0f);
            float var  = sxx * (1.0f / 32.0f) - mean * mean;
            float rs   = rsqrtf(var + 1e-5f);

            float xn[8];
            #pragma unroll
            for (int k = 0; k < 8; ++k) xn[k] = fmaf((xv[k] - mean) * rs, g_r[k], e_r[k]);

            uint4 yw;
            yw.x = (f2bf_rne(xn[1]) << 16) | f2bf_rne(xn[0]);
            yw.y = (f2bf_rne(xn[3]) << 16) | f2bf_rne(xn[2]);
            yw.z = (f2bf_rne(xn[5]) << 16) | f2bf_rne(xn[4]);
            yw.w = (f2bf_rne(xn[7]) << 16) | f2bf_rne(xn[6]);
            *(uint4*)(yb + (size_t)(t * RSTEP + rg) * Dn + col0) = yw;

            #pragma unroll
            for (int s = 0; s < 4; ++s) {
                float lg = fmaf(rs, fmaf(-mean, qgs[s], ds[s]), qe[s]);
                float w  = __expf(lg);                    // logits ~ +-1.3
                ps[s] += w;
                #pragma unroll
                for (int k = 0; k < 8; ++k) pa[s][k] = fmaf(w, xn[k], pa[s][k]);
            }
            v0 = n0; v1 = n1;
        }
    } else {
        float qt_r[4][8];
        #pragma unroll
        for (int s = 0; s < 4; ++s)
            #pragma unroll
            for (int k = 0; k < 8; ++k) qt_r[s][k] = qt_sh[s][col0 + k];

        const unsigned short* yb = y + ((size_t)b * Nn + (size_t)c * RPB) * Dn;
        uint4 cv = *(const uint4*)(yb + (size_t)rg * Dn + col0);

        for (int t = 0; t < NSTEP; ++t) {
            const int tn = (t + 1 < NSTEP) ? t + 1 : t;
            uint4 nv = *(const uint4*)(yb + (size_t)(tn * RSTEP + rg) * Dn + col0);

            float yv[8];
            yv[0] = bflo2f(cv.x); yv[1] = bfhi2f(cv.x);
            yv[2] = bflo2f(cv.y); yv[3] = bfhi2f(cv.y);
            yv[4] = bflo2f(cv.z); yv[5] = bfhi2f(cv.z);
            yv[6] = bflo2f(cv.w); yv[7] = bfhi2f(cv.w);

            float ds[4] = {0.f, 0.f, 0.f, 0.f};
            #pragma unroll
            for (int k = 0; k < 8; ++k)
                #pragma unroll
                for (int s = 0; s < 4; ++s) ds[s] = fmaf(yv[k], qt_r[s][k], ds[s]);
            #pragma unroll
            for (int s = 0; s < 4; ++s) ds[s] += __shfl_xor(ds[s], 1);
            #pragma unroll
            for (int s = 0; s < 4; ++s) ds[s] += __shfl_xor(ds[s], 2);

            #pragma unroll
            for (int s = 0; s < 4; ++s) {
                float w = __expf(ds[s]);
                ps[s] += w;
                #pragma unroll
                for (int k = 0; k < 8; ++k) pa[s][k] = fmaf(w, yv[k], pa[s][k]);
            }
            cv = nv;
        }
    }

    // butterfly across the 16 row-groups of each wave (sub stays fixed)
    #pragma unroll
    for (int m = 4; m <= 32; m <<= 1) {
        #pragma unroll
        for (int s = 0; s < 4; ++s) {
            ps[s] += __shfl_xor(ps[s], m);
            #pragma unroll
            for (int k = 0; k < 8; ++k) pa[s][k] += __shfl_xor(pa[s][k], m);
        }
    }
    const int wv = tid >> 6, lane = tid & 63;
    if (lane < 4) {
        #pragma unroll
        for (int s = 0; s < 4; ++s)
            #pragma unroll
            for (int k = 0; k < 8; ++k) ls_pa[wv][s][lane * 8 + k] = pa[s][k];
        if (lane == 0) {
            #pragma unroll
            for (int s = 0; s < 4; ++s) ls_ps[wv][s] = ps[s];
        }
    }
    __syncthreads();
    if (tid < 128) {
        const int s = tid >> 5, d = tid & 31;
        float a = ls_pa[0][s][d] + ls_pa[1][s][d] + ls_pa[2][s][d] + ls_pa[3][s][d];
        pa_cur[(((size_t)b * Cn + c) * Sn + s) * Dn + d] = a;
        if (d == 0)
            ps_cur[((size_t)b * Cn + c) * Sn + s] =
                ls_ps[0][s] + ls_ps[1][s] + ls_ps[2][s] + ls_ps[3][s];
    }
}

// ---------------------------------------------------------------------------
__global__ __launch_bounds__(128)
void final_k(const float* __restrict__ Wv,
             const float* __restrict__ Wih, const float* __restrict__ Whh,
             const float* __restrict__ bih, const float* __restrict__ bhh,
             const float* __restrict__ W1, const float* __restrict__ b1v,
             const float* __restrict__ W2, const float* __restrict__ b2v,
             const float* __restrict__ lns_g, const float* __restrict__ lns_b,
             const float* __restrict__ lnff_g, const float* __restrict__ lnff_b,
             const float* __restrict__ Wq, const float* __restrict__ Wk,
             const float* __restrict__ slots_prev,
             const float* __restrict__ pa_prev, const float* __restrict__ ps_prev,
             float* __restrict__ out)
{
    const int b = blockIdx.x, tid = threadIdx.x;
    __shared__ float qt_sh[Sn][Dn], ta[Sn][Dn], tb[Sn][Dn];
    chain_fn<1, 0>(b, tid, pa_prev, ps_prev, slots_prev,
        nullptr, nullptr, nullptr, Wv, Wih, Whh, bih, bhh, W1, b1v, W2, b2v,
        lns_g, lns_b, lnff_g, lnff_b, Wq, Wk, qt_sh, ta, tb, out);
}

// ---------------------------------------------------------------------------
// Fallback: proven single fused kernel (round 3, 163 us) if ws is too small.
// ---------------------------------------------------------------------------
#define TPB 1024
#define NW (TPB / 64)
#define RPS (TPB / 4)
#define STEPS (Nn / RPS)

__global__ __launch_bounds__(TPB)
void slot_fused(const float* __restrict__ x, const float* __restrict__ noise,
                const float* __restrict__ mu, const float* __restrict__ logsig,
                const float* __restrict__ Wq, const float* __restrict__ Wk,
                const float* __restrict__ Wv,
                const float* __restrict__ Wih, const float* __restrict__ Whh,
                const float* __restrict__ bih, const float* __restrict__ bhh,
                const float* __restrict__ W1, const float* __restrict__ b1v,
                const float* __restrict__ W2, const float* __restrict__ b2v,
                const float* __restrict__ lnx_g, const float* __restrict__ lnx_b,
                const float* __restrict__ lns_g, const float* __restrict__ lns_b,
                const float* __restrict__ lnff_g, const float* __restrict__ lnff_b,
                float* __restrict__ out)
{
    const int b   = blockIdx.x;
    const int tid = threadIdx.x;
    __shared__ float slots_sh[Sn][Dn];
    __shared__ float qt_sh[Sn][Dn];
    __shared__ float a_sh[Sn][Dn];
    __shared__ float b_sh[Sn][Dn];
    __shared__ float h_sh[Sn][Dn];
    __shared__ float ls_u[NW][Sn][Dn];
    __shared__ float ls_s[NW][Sn];
    const int s128 = tid >> 5, d128 = tid & 31;

    if (tid < 128) {
        float sv = mu[d128] + noise[(b * Sn + s128) * Dn + d128] * __expf(logsig[d128]);
        slots_sh[s128][d128] = sv;
        float sx = sv, sxx = sv * sv;
        #pragma unroll
        for (int m = 1; m <= 16; m <<= 1) { sx += __shfl_xor(sx, m); sxx += __shfl_xor(sxx, m); }
        float mean = sx * (1.0f / 32.0f);
        float var  = sxx * (1.0f / 32.0f) - mean * mean;
        a_sh[s128][d128] = (sv - mean) * rsqrtf(var + 1e-5f) * lns_g[d128] + lns_b[d128];
    }
    __syncthreads();
    if (tid < 128) {
        float q = 0.f;
        #pragma unroll 8
        for (int j = 0; j < 32; ++j) q = fmaf(Wq[d128 * 32 + j], a_sh[s128][j], q);
        b_sh[s128][d128] = q;
    }
    __syncthreads();
    if (tid < 128) {
        float qv = 0.f;
        #pragma unroll 8
        for (int i = 0; i < 32; ++i) qv = fmaf(b_sh[s128][i], Wk[i * 32 + d128], qv);
        qt_sh[s128][d128] = qv * SCALE;
    }
    __syncthreads();

    const int sub = tid & 3, col0 = sub * 8;
    const int rg  = tid >> 2;
    float g_r[8], e_r[8];
    #pragma unroll
    for (int k = 0; k < 8; ++k) { g_r[k] = lnx_g[col0 + k]; e_r[k] = lnx_b[col0 + k]; }
    const float* xb = x + (size_t)b * Nn * Dn;
    float sv_reg = 0.f;

    for (int it = 0; it < 3; ++it) {
        float qt_r[4][8];
        #pragma unroll
        for (int s = 0; s < 4; ++s)
            #pragma unroll
            for (int k = 0; k < 8; ++k) qt_r[s][k] = qt_sh[s][col0 + k];
        float pu[4][8];
        float ps[4] = {0.f, 0.f, 0.f, 0.f};
        #pragma unroll
        for (int s = 0; s < 4; ++s)
            #pragma unroll
            for (int k = 0; k < 8; ++k) pu[s][k] = 0.f;

        const float* xr0 = xb + (size_t)rg * Dn + col0;
        float4 v0 = *(const float4*)(xr0);
        float4 v1 = *(const float4*)(xr0 + 4);
        #pragma unroll 2
        for (int t = 0; t < STEPS; ++t) {
            const float* xrn = xb + (size_t)((((t + 1) & (STEPS - 1)) * RPS) + rg) * Dn + col0;
            float4 n0 = *(const float4*)(xrn);
            float4 n1 = *(const float4*)(xrn + 4);
            float xv[8] = {v0.x, v0.y, v0.z, v0.w, v1.x, v1.y, v1.z, v1.w};
            float sx = 0.f, sxx = 0.f;
            #pragma unroll
            for (int k = 0; k < 8; ++k) { sx += xv[k]; sxx = fmaf(xv[k], xv[k], sxx); }
            sx += __shfl_xor(sx, 1); sxx += __shfl_xor(sxx, 1);
            sx += __shfl_xor(sx, 2); sxx += __shfl_xor(sxx, 2);
            float mean = sx * (1.0f / 32.0f);
            float var  = sxx * (1.0f / 32.0f) - mean * mean;
            float rs   = rsqrtf(var + 1e-5f);
            float xn[8];
            #pragma unroll
            for (int k = 0; k < 8; ++k) xn[k] = fmaf((xv[k] - mean) * rs, g_r[k], e_r[k]);
            #pragma unroll
            for (int s = 0; s < 4; ++s) {
                float a = 0.f;
                #pragma unroll
                for (int k = 0; k < 8; ++k) a = fmaf(xn[k], qt_r[s][k], a);
                a += __shfl_xor(a, 1);
                a += __shfl_xor(a, 2);
                float w = __expf(a);
                ps[s] += w;
                #pragma unroll
                for (int k = 0; k < 8; ++k) pu[s][k] = fmaf(w, xn[k], pu[s][k]);
            }
            v0 = n0; v1 = n1;
        }
        #pragma unroll
        for (int m = 4; m <= 32; m <<= 1) {
            #pragma unroll
            for (int s = 0; s < 4; ++s) {
                ps[s] += __shfl_xor(ps[s], m);
                #pragma unroll
                for (int k = 0; k < 8; ++k) pu[s][k] += __shfl_xor(pu[s][k], m);
            }
        }
        {
            const int wv = tid >> 6, lane = tid & 63;
            if (lane < 4) {
                #pragma unroll
                for (int s = 0; s < 4; ++s)
                    #pragma unroll
                    for (int k = 0; k < 8; ++k) ls_u[wv][s][lane * 8 + k] = pu[s][k];
                if (lane == 0) {
                    #pragma unroll
                    for (int s = 0; s < 4; ++s) ls_s[wv][s] = ps[s];
                }
            }
        }
        __syncthreads();
        if (tid < 128) {
            float u = 0.f, ss = 0.f;
            #pragma unroll
            for (int w = 0; w < NW; ++w) { u += ls_u[w][s128][d128]; ss += ls_s[w][s128]; }
            a_sh[s128][d128] = (u / ss) * RENORM;
        }
        __syncthreads();
        if (tid < 128) {
            float upd = 0.f;
            #pragma unroll 8
            for (int j = 0; j < 32; ++j) upd = fmaf(Wv[d128 * 32 + j], a_sh[s128][j], upd);
            b_sh[s128][d128] = upd;
        }
        __syncthreads();
        if (tid < 128) {
            float gi[3], gh[3];
            #pragma unroll
            for (int g3 = 0; g3 < 3; ++g3) {
                const int row = g3 * 32 + d128;
                float a1 = bih[row], a2 = bhh[row];
                #pragma unroll 8
                for (int j = 0; j < 32; ++j) {
                    a1 = fmaf(Wih[row * 32 + j], b_sh[s128][j], a1);
                    a2 = fmaf(Whh[row * 32 + j], slots_sh[s128][j], a2);
                }
                gi[g3] = a1; gh[g3] = a2;
            }
            float r  = sigmoidf_(gi[0] + gh[0]);
            float z  = sigmoidf_(gi[1] + gh[1]);
            float nn = tanhf(gi[2] + r * gh[2]);
            sv_reg = (1.0f - z) * nn + z * slots_sh[s128][d128];
            float sx = sv_reg, sxx = sv_reg * sv_reg;
            #pragma unroll
            for (int m = 1; m <= 16; m <<= 1) { sx += __shfl_xor(sx, m); sxx += __shfl_xor(sxx, m); }
            float mean = sx * (1.0f / 32.0f);
            float var  = sxx * (1.0f / 32.0f) - mean * mean;
            a_sh[s128][d128] = (sv_reg - mean) * rsqrtf(var + 1e-5f) * lnff_g[d128] + lnff_b[d128];
        }
        __syncthreads();
        if (tid < 128) {
            float h = b1v[d128];
            #pragma unroll 8
            for (int j = 0; j < 32; ++j) h = fmaf(W1[d128 * 32 + j], a_sh[s128][j], h);
            h_sh[s128][d128] = fmaxf(h, 0.f);
        }
        __syncthreads();
        if (tid < 128) {
            float o = b2v[d128];
            #pragma unroll 8
            for (int j = 0; j < 32; ++j) o = fmaf(W2[d128 * 32 + j], h_sh[s128][j], o);
            float sfin = sv_reg + o;
            slots_sh[s128][d128] = sfin;
            if (it < 2) {
                float sx = sfin, sxx = sfin * sfin;
                #pragma unroll
                for (int m = 1; m <= 16; m <<= 1) { sx += __shfl_xor(sx, m); sxx += __shfl_xor(sxx, m); }
                float mean = sx * (1.0f / 32.0f);
                float var  = sxx * (1.0f / 32.0f) - mean * mean;
                a_sh[s128][d128] = (sfin - mean) * rsqrtf(var + 1e-5f) * lns_g[d128] + lns_b[d128];
            }
        }
        __syncthreads();
        if (it < 2) {
            if (tid < 128) {
                float q = 0.f;
                #pragma unroll 8
                for (int j = 0; j < 32; ++j) q = fmaf(Wq[d128 * 32 + j], a_sh[s128][j], q);
                b_sh[s128][d128] = q;
            }
            __syncthreads();
            if (tid < 128) {
                float qv = 0.f;
                #pragma unroll 8
                for (int i = 0; i < 32; ++i) qv = fmaf(b_sh[s128][i], Wk[i * 32 + d128], qv);
                qt_sh[s128][d128] = qv * SCALE;
            }
            __syncthreads();
        }
    }
    if (tid < 128)
        out[(size_t)b * 128 + tid] = slots_sh[s128][d128];
}

// ---------------------------------------------------------------------------
extern "C" void kernel_launch(void* const* d_in, const int* in_sizes, int n_in,
                              void* d_out, int out_size, void* d_ws, size_t ws_size,
                              hipStream_t stream)
{
    const float* x      = (const float*)d_in[0];
    const float* noise  = (const float*)d_in[1];
    const float* mu     = (const float*)d_in[2];
    const float* logsig = (const float*)d_in[3];
    const float* Wq     = (const float*)d_in[4];
    const float* Wk     = (const float*)d_in[5];
    const float* Wv     = (const float*)d_in[6];
    const float* Wih    = (const float*)d_in[7];
    const float* Whh    = (const float*)d_in[8];
    const float* bih    = (const float*)d_in[9];
    const float* bhh    = (const float*)d_in[10];
    const float* W1     = (const float*)d_in[11];
    const float* b1v    = (const float*)d_in[12];
    const float* W2     = (const float*)d_in[13];
    const float* b2v    = (const float*)d_in[14];
    const float* lnx_g  = (const float*)d_in[15];
    const float* lnx_b  = (const float*)d_in[16];
    const float* lns_g  = (const float*)d_in[17];
    const float* lns_b  = (const float*)d_in[18];
    const float* lnff_g = (const float*)d_in[19];
    const float* lnff_b = (const float*)d_in[20];
    float* out = (float*)d_out;

    if (ws_size >= WS_REQ) {
        float* wsf    = (float*)d_ws;
        float* slots0 = wsf;
        float* slots1 = slots0 + Bn * Sn * Dn;
        float* slots2 = slots1 + Bn * Sn * Dn;
        float* pa0    = slots2 + Bn * Sn * Dn;
        float* pa1    = pa0 + Bn * Cn * Sn * Dn;
        float* pa2    = pa1 + Bn * Cn * Sn * Dn;
        float* ps0    = pa2 + Bn * Cn * Sn * Dn;
        float* ps1    = ps0 + Bn * Cn * Sn;
        float* ps2    = ps1 + Bn * Cn * Sn;
        unsigned short* ybuf = (unsigned short*)(ps2 + Bn * Cn * Sn);

        pass_k<0><<<dim3(Cn, Bn), PT, 0, stream>>>(x, ybuf, noise, mu, logsig,
            Wq, Wk, Wv, Wih, Whh, bih, bhh, W1, b1v, W2, b2v,
            lnx_g, lnx_b, lns_g, lns_b, lnff_g, lnff_b,
            nullptr, slots0, nullptr, nullptr, pa0, ps0);
        pass_k<1><<<dim3(Cn, Bn), PT, 0, stream>>>(x, ybuf, noise, mu, logsig,
            Wq, Wk, Wv, Wih, Whh, bih, bhh, W1, b1v, W2, b2v,
            lnx_g, lnx_b, lns_g, lns_b, lnff_g, lnff_b,
            slots0, slots1, pa0, ps0, pa1, ps1);
        pass_k<2><<<dim3(Cn, Bn), PT, 0, stream>>>(x, ybuf, noise, mu, logsig,
            Wq, Wk, Wv, Wih, Whh, bih, bhh, W1, b1v, W2, b2v,
            lnx_g, lnx_b, lns_g, lns_b, lnff_g, lnff_b,
            slots1, slots2, pa1, ps1, pa2, ps2);
        final_k<<<Bn, 128, 0, stream>>>(Wv, Wih, Whh, bih, bhh, W1, b1v, W2, b2v,
            lns_g, lns_b, lnff_g, lnff_b, Wq, Wk, slots2, pa2, ps2, out);
    } else {
        slot_fused<<<Bn, TPB, 0, stream>>>(x, noise, mu, logsig, Wq, Wk, Wv,
                                           Wih, Whh, bih, bhh, W1, b1v, W2, b2v,
                                           lnx_g, lnx_b, lns_g, lns_b, lnff_g, lnff_b,
                                           out);
    }
}

// Round 7
// 135.487 us; speedup vs baseline: 1.2791x; 1.2791x over previous
//
#include <hip/hip_runtime.h>
#include <hip/hip_bf16.h>

// SlotAttention: B=128, N=8192, S=4, D=32, ITERS=3.  Output dtype: float32.
//
// 4 launches, ILP=2 streaming passes over fp32 x (no y-cache: passes are
// latency-chain-bound, not byte-bound -- round-6 evidence):
//   pass<0>: prologue init slots0,qt0; stream x, accumulate it-0 partials.
//   pass<1>: prologue update->slots1,qt1 from it-0 partials; stream x.
//   pass<2>: prologue update->slots2,qt2; stream x.
//   final  : update -> slots3 -> out (fp32).
// Folded-LN algebra (round 4): logit_s = rs*(qg_s.x - mean*qgs_s) + qe_s,
// u = gamma o (Sum al*x - Sum al*mean) + (Sum w) beta, al = w*rs.
// Each thread handles TWO rows per step (independent chains, shared
// accumulators) with prefetch, to double work per shuffle/load wait.

#define Bn 128
#define Nn 8192
#define Sn 4
#define Dn 32
#define SCALE 0.17677669529663687f   // D^-0.5
#define RENORM (1.0f / (1.0f + (float)Nn * 1e-8f))

#define Cn 8                   // chunks per batch -> grid 1024 blocks
#define RPB (Nn / Cn)          // 1024 rows per block
#define PT 256                 // 4 waves
#define RSTEP 128              // rows per step (2 rows per thread-slot)
#define NSTEP (RPB / RSTEP)    // 8 steps

#define WS_REQ ((size_t)(3 * Bn * Sn * Dn + 3 * Bn * Cn * Sn * Dn + 6 * Bn * Cn * Sn) * 4)

__device__ __forceinline__ float sigmoidf_(float v) { return 1.0f / (1.0f + __expf(-v)); }

// ---------------------------------------------------------------------------
// chain: compute slots_i (KIND=0: init; KIND=1: GRU/MLP update from partials)
// and optionally qt_i into qt_sh. Uniform syncs; threads >=128 idle through.
// ---------------------------------------------------------------------------
template<int KIND, int WANT_QT>
__device__ __forceinline__ void chain_fn(
    int b, int tid,
    const float* __restrict__ pa_prev, const float* __restrict__ pb_prev,
    const float* __restrict__ ps_prev,
    const float* __restrict__ slots_prev,
    const float* __restrict__ noise, const float* __restrict__ mu,
    const float* __restrict__ logsig,
    const float* __restrict__ lnx_g, const float* __restrict__ lnx_b,
    const float* __restrict__ Wv,
    const float* __restrict__ Wih, const float* __restrict__ Whh,
    const float* __restrict__ bih, const float* __restrict__ bhh,
    const float* __restrict__ W1, const float* __restrict__ b1v,
    const float* __restrict__ W2, const float* __restrict__ b2v,
    const float* __restrict__ lns_g, const float* __restrict__ lns_b,
    const float* __restrict__ lnff_g, const float* __restrict__ lnff_b,
    const float* __restrict__ Wq, const float* __restrict__ Wk,
    float (*qt_sh)[Dn], float (*ta)[Dn], float (*tb)[Dn],
    float* __restrict__ store)
{
    const int s = (tid >> 5) & 3, d = tid & 31;
    const bool act = tid < 128;
    float sfin = 0.f;

    if constexpr (KIND == 0) {
        if (act)
            sfin = mu[d] + noise[(b * Sn + s) * Dn + d] * __expf(logsig[d]);
    } else {
        float sv_c = 0.f, lnffv = 0.f;
        if (act) {
            float PA = 0.f, PB = 0.f, PS = 0.f;
            #pragma unroll
            for (int c = 0; c < Cn; ++c) {
                PA += pa_prev[(((size_t)b * Cn + c) * Sn + s) * Dn + d];
                PB += pb_prev[((size_t)b * Cn + c) * Sn + s];
                PS += ps_prev[((size_t)b * Cn + c) * Sn + s];
            }
            float u = fmaf(lnx_g[d], PA - PB, PS * lnx_b[d]);
            ta[s][d] = (u / PS) * RENORM;                 // ubar
            tb[s][d] = slots_prev[(b * Sn + s) * Dn + d]; // sold
        }
        __syncthreads();
        float updv = 0.f;
        if (act) {
            #pragma unroll 8
            for (int j = 0; j < 32; ++j) updv = fmaf(Wv[d * 32 + j], ta[s][j], updv);
        }
        __syncthreads();
        if (act) ta[s][d] = updv;                        // upd
        __syncthreads();
        if (act) {
            float gi[3], gh[3];
            #pragma unroll
            for (int g3 = 0; g3 < 3; ++g3) {
                const int row = g3 * 32 + d;
                float a1 = bih[row], a2 = bhh[row];
                #pragma unroll 8
                for (int j = 0; j < 32; ++j) {
                    a1 = fmaf(Wih[row * 32 + j], ta[s][j], a1);
                    a2 = fmaf(Whh[row * 32 + j], tb[s][j], a2);
                }
                gi[g3] = a1; gh[g3] = a2;
            }
            float r  = sigmoidf_(gi[0] + gh[0]);
            float z  = sigmoidf_(gi[1] + gh[1]);
            float nn = tanhf(gi[2] + r * gh[2]);
            sv_c = (1.0f - z) * nn + z * tb[s][d];
            float sx = sv_c, sxx = sv_c * sv_c;
            #pragma unroll
            for (int m = 1; m <= 16; m <<= 1) { sx += __shfl_xor(sx, m); sxx += __shfl_xor(sxx, m); }
            float mean = sx * (1.0f / 32.0f);
            float var  = sxx * (1.0f / 32.0f) - mean * mean;
            lnffv = (sv_c - mean) * rsqrtf(var + 1e-5f) * lnff_g[d] + lnff_b[d];
        }
        __syncthreads();
        if (act) ta[s][d] = lnffv;
        __syncthreads();
        if (act) {
            float h = b1v[d];
            #pragma unroll 8
            for (int j = 0; j < 32; ++j) h = fmaf(W1[d * 32 + j], ta[s][j], h);
            tb[s][d] = fmaxf(h, 0.f);
        }
        __syncthreads();
        if (act) {
            float o = b2v[d];
            #pragma unroll 8
            for (int j = 0; j < 32; ++j) o = fmaf(W2[d * 32 + j], tb[s][j], o);
            sfin = sv_c + o;
        }
    }

    if (act && store) store[(b * Sn + s) * Dn + d] = sfin;

    if constexpr (WANT_QT) {
        float lnsv = 0.f;
        if (act) {
            float sx = sfin, sxx = sfin * sfin;
            #pragma unroll
            for (int m = 1; m <= 16; m <<= 1) { sx += __shfl_xor(sx, m); sxx += __shfl_xor(sxx, m); }
            float mean = sx * (1.0f / 32.0f);
            float var  = sxx * (1.0f / 32.0f) - mean * mean;
            lnsv = (sfin - mean) * rsqrtf(var + 1e-5f) * lns_g[d] + lns_b[d];
        }
        __syncthreads();
        if (act) ta[s][d] = lnsv;
        __syncthreads();
        if (act) {
            float q = 0.f;
            #pragma unroll 8
            for (int j = 0; j < 32; ++j) q = fmaf(Wq[d * 32 + j], ta[s][j], q);
            tb[s][d] = q;
        }
        __syncthreads();
        if (act) {
            float qv = 0.f;
            #pragma unroll 8
            for (int i = 0; i < 32; ++i) qv = fmaf(tb[s][i], Wk[i * 32 + d], qv);
            qt_sh[s][d] = qv * SCALE;
        }
        __syncthreads();
    }
}

// ---------------------------------------------------------------------------
// pass kernel: prologue chain, then stream 1024 rows with 2 rows/thread/step.
// ---------------------------------------------------------------------------
template<int IT>
__global__ __launch_bounds__(PT)
void pass_k(const float* __restrict__ x,
            const float* __restrict__ noise, const float* __restrict__ mu,
            const float* __restrict__ logsig,
            const float* __restrict__ Wq, const float* __restrict__ Wk,
            const float* __restrict__ Wv,
            const float* __restrict__ Wih, const float* __restrict__ Whh,
            const float* __restrict__ bih, const float* __restrict__ bhh,
            const float* __restrict__ W1, const float* __restrict__ b1v,
            const float* __restrict__ W2, const float* __restrict__ b2v,
            const float* __restrict__ lnx_g, const float* __restrict__ lnx_b,
            const float* __restrict__ lns_g, const float* __restrict__ lns_b,
            const float* __restrict__ lnff_g, const float* __restrict__ lnff_b,
            const float* __restrict__ slots_prev, float* __restrict__ slots_cur,
            const float* __restrict__ pa_prev, const float* __restrict__ pb_prev,
            const float* __restrict__ ps_prev,
            float* __restrict__ pa_cur, float* __restrict__ pb_cur,
            float* __restrict__ ps_cur)
{
    const int c = blockIdx.x, b = blockIdx.y, tid = threadIdx.x;
    __shared__ float qt_sh[Sn][Dn], ta[Sn][Dn], tb[Sn][Dn];
    __shared__ float ls_pa[4][Sn][Dn];
    __shared__ float ls_pb[4][Sn];
    __shared__ float ls_ps[4][Sn];

    chain_fn<(IT == 0 ? 0 : 1), 1>(b, tid, pa_prev, pb_prev, ps_prev, slots_prev,
        noise, mu, logsig, lnx_g, lnx_b, Wv, Wih, Whh, bih, bhh, W1, b1v, W2, b2v,
        lns_g, lns_b, lnff_g, lnff_b, Wq, Wk,
        qt_sh, ta, tb, (c == 0) ? slots_cur : nullptr);

    const int sub = tid & 3, col0 = sub * 8, rg = tid >> 2;  // rg 0..63

    // prologue: qg = qt*gamma ; qgs = sum(qg) ; qe = qt.beta
    float qg[4][8], qgs[4], qe[4];
    {
        float g8[8], e8[8];
        #pragma unroll
        for (int k = 0; k < 8; ++k) { g8[k] = lnx_g[col0 + k]; e8[k] = lnx_b[col0 + k]; }
        #pragma unroll
        for (int s = 0; s < 4; ++s) {
            float sg = 0.f, se = 0.f;
            #pragma unroll
            for (int k = 0; k < 8; ++k) {
                float q = qt_sh[s][col0 + k];
                qg[s][k] = q * g8[k];
                sg += qg[s][k];
                se = fmaf(q, e8[k], se);
            }
            sg += __shfl_xor(sg, 1); sg += __shfl_xor(sg, 2);
            se += __shfl_xor(se, 1); se += __shfl_xor(se, 2);
            qgs[s] = sg; qe[s] = se;
        }
    }

    float pa[4][8], pb[4] = {0.f,0.f,0.f,0.f}, ps[4] = {0.f,0.f,0.f,0.f};
    #pragma unroll
    for (int s = 0; s < 4; ++s)
        #pragma unroll
        for (int k = 0; k < 8; ++k) pa[s][k] = 0.f;

    const float* xb = x + ((size_t)b * Nn + (size_t)c * RPB) * Dn;
    const float* pA0 = xb + (size_t)rg * Dn + col0;
    const float* pB0 = pA0 + 64 * Dn;
    float4 a0 = *(const float4*)(pA0);
    float4 a1 = *(const float4*)(pA0 + 4);
    float4 b0 = *(const float4*)(pB0);
    float4 b1 = *(const float4*)(pB0 + 4);

    for (int t = 0; t < NSTEP; ++t) {
        const int tn = (t + 1 < NSTEP) ? t + 1 : t;
        const float* qA = xb + (size_t)(tn * RSTEP + rg) * Dn + col0;
        const float* qB = qA + 64 * Dn;
        float4 nA0 = *(const float4*)(qA);
        float4 nA1 = *(const float4*)(qA + 4);
        float4 nB0 = *(const float4*)(qB);
        float4 nB1 = *(const float4*)(qB + 4);

        float xA[8] = {a0.x, a0.y, a0.z, a0.w, a1.x, a1.y, a1.z, a1.w};
        float xB[8] = {b0.x, b0.y, b0.z, b0.w, b1.x, b1.y, b1.z, b1.w};

        // two independent 6-stream accumulations
        float sxA = 0.f, sxxA = 0.f, dA[4] = {0.f,0.f,0.f,0.f};
        float sxB = 0.f, sxxB = 0.f, dB[4] = {0.f,0.f,0.f,0.f};
        #pragma unroll
        for (int k = 0; k < 8; ++k) {
            sxA += xA[k];  sxxA = fmaf(xA[k], xA[k], sxxA);
            sxB += xB[k];  sxxB = fmaf(xB[k], xB[k], sxxB);
            #pragma unroll
            for (int s = 0; s < 4; ++s) {
                dA[s] = fmaf(xA[k], qg[s][k], dA[s]);
                dB[s] = fmaf(xB[k], qg[s][k], dB[s]);
            }
        }
        // batched level-1 shuffles (one wait), then level-2 (one wait)
        sxA += __shfl_xor(sxA, 1); sxxA += __shfl_xor(sxxA, 1);
        sxB += __shfl_xor(sxB, 1); sxxB += __shfl_xor(sxxB, 1);
        #pragma unroll
        for (int s = 0; s < 4; ++s) { dA[s] += __shfl_xor(dA[s], 1); dB[s] += __shfl_xor(dB[s], 1); }
        sxA += __shfl_xor(sxA, 2); sxxA += __shfl_xor(sxxA, 2);
        sxB += __shfl_xor(sxB, 2); sxxB += __shfl_xor(sxxB, 2);
        #pragma unroll
        for (int s = 0; s < 4; ++s) { dA[s] += __shfl_xor(dA[s], 2); dB[s] += __shfl_xor(dB[s], 2); }

        float meanA = sxA * (1.0f / 32.0f);
        float varA  = sxxA * (1.0f / 32.0f) - meanA * meanA;
        float rsA   = rsqrtf(varA + 1e-5f);
        float meanB = sxB * (1.0f / 32.0f);
        float varB  = sxxB * (1.0f / 32.0f) - meanB * meanB;
        float rsB   = rsqrtf(varB + 1e-5f);

        #pragma unroll
        for (int s = 0; s < 4; ++s) {
            float lgA = fmaf(rsA, fmaf(-meanA, qgs[s], dA[s]), qe[s]);
            float lgB = fmaf(rsB, fmaf(-meanB, qgs[s], dB[s]), qe[s]);
            float wA = __expf(lgA), wB = __expf(lgB);      // |logit| <~ 8
            float alA = wA * rsA,  alB = wB * rsB;
            ps[s] += wA + wB;
            pb[s] = fmaf(alA, meanA, fmaf(alB, meanB, pb[s]));
            #pragma unroll
            for (int k = 0; k < 8; ++k)
                pa[s][k] = fmaf(alA, xA[k], fmaf(alB, xB[k], pa[s][k]));
        }
        a0 = nA0; a1 = nA1; b0 = nB0; b1 = nB1;
    }

    // butterfly across the 16 row-groups of each wave (sub stays fixed)
    #pragma unroll
    for (int m = 4; m <= 32; m <<= 1) {
        #pragma unroll
        for (int s = 0; s < 4; ++s) {
            ps[s] += __shfl_xor(ps[s], m);
            pb[s] += __shfl_xor(pb[s], m);
            #pragma unroll
            for (int k = 0; k < 8; ++k) pa[s][k] += __shfl_xor(pa[s][k], m);
        }
    }

    const int wv = tid >> 6, lane = tid & 63;
    if (lane < 4) {
        #pragma unroll
        for (int s = 0; s < 4; ++s)
            #pragma unroll
            for (int k = 0; k < 8; ++k) ls_pa[wv][s][lane * 8 + k] = pa[s][k];
        if (lane == 0) {
            #pragma unroll
            for (int s = 0; s < 4; ++s) { ls_pb[wv][s] = pb[s]; ls_ps[wv][s] = ps[s]; }
        }
    }
    __syncthreads();
    if (tid < 128) {
        const int s = tid >> 5, d = tid & 31;
        float a = ls_pa[0][s][d] + ls_pa[1][s][d] + ls_pa[2][s][d] + ls_pa[3][s][d];
        pa_cur[(((size_t)b * Cn + c) * Sn + s) * Dn + d] = a;
        if (d == 0) {
            pb_cur[((size_t)b * Cn + c) * Sn + s] =
                ls_pb[0][s] + ls_pb[1][s] + ls_pb[2][s] + ls_pb[3][s];
            ps_cur[((size_t)b * Cn + c) * Sn + s] =
                ls_ps[0][s] + ls_ps[1][s] + ls_ps[2][s] + ls_ps[3][s];
        }
    }
}

// ---------------------------------------------------------------------------
__global__ __launch_bounds__(128)
void final_k(const float* __restrict__ lnx_g, const float* __restrict__ lnx_b,
             const float* __restrict__ Wv,
             const float* __restrict__ Wih, const float* __restrict__ Whh,
             const float* __restrict__ bih, const float* __restrict__ bhh,
             const float* __restrict__ W1, const float* __restrict__ b1v,
             const float* __restrict__ W2, const float* __restrict__ b2v,
             const float* __restrict__ lns_g, const float* __restrict__ lns_b,
             const float* __restrict__ lnff_g, const float* __restrict__ lnff_b,
             const float* __restrict__ Wq, const float* __restrict__ Wk,
             const float* __restrict__ slots_prev,
             const float* __restrict__ pa_prev, const float* __restrict__ pb_prev,
             const float* __restrict__ ps_prev,
             float* __restrict__ out)
{
    const int b = blockIdx.x, tid = threadIdx.x;
    __shared__ float qt_sh[Sn][Dn], ta[Sn][Dn], tb[Sn][Dn];
    chain_fn<1, 0>(b, tid, pa_prev, pb_prev, ps_prev, slots_prev,
        nullptr, nullptr, nullptr, lnx_g, lnx_b,
        Wv, Wih, Whh, bih, bhh, W1, b1v, W2, b2v,
        lns_g, lns_b, lnff_g, lnff_b, Wq, Wk, qt_sh, ta, tb, out);
}

// ---------------------------------------------------------------------------
// Fallback: proven single fused kernel (round 3, 163 us) if ws is too small.
// ---------------------------------------------------------------------------
#define TPB 1024
#define NW (TPB / 64)
#define RPS (TPB / 4)
#define STEPS (Nn / RPS)

__global__ __launch_bounds__(TPB)
void slot_fused(const float* __restrict__ x, const float* __restrict__ noise,
                const float* __restrict__ mu, const float* __restrict__ logsig,
                const float* __restrict__ Wq, const float* __restrict__ Wk,
                const float* __restrict__ Wv,
                const float* __restrict__ Wih, const float* __restrict__ Whh,
                const float* __restrict__ bih, const float* __restrict__ bhh,
                const float* __restrict__ W1, const float* __restrict__ b1v,
                const float* __restrict__ W2, const float* __restrict__ b2v,
                const float* __restrict__ lnx_g, const float* __restrict__ lnx_b,
                const float* __restrict__ lns_g, const float* __restrict__ lns_b,
                const float* __restrict__ lnff_g, const float* __restrict__ lnff_b,
                float* __restrict__ out)
{
    const int b   = blockIdx.x;
    const int tid = threadIdx.x;
    __shared__ float slots_sh[Sn][Dn];
    __shared__ float qt_sh[Sn][Dn];
    __shared__ float a_sh[Sn][Dn];
    __shared__ float b_sh[Sn][Dn];
    __shared__ float h_sh[Sn][Dn];
    __shared__ float ls_u[NW][Sn][Dn];
    __shared__ float ls_s[NW][Sn];
    const int s128 = tid >> 5, d128 = tid & 31;

    if (tid < 128) {
        float sv = mu[d128] + noise[(b * Sn + s128) * Dn + d128] * __expf(logsig[d128]);
        slots_sh[s128][d128] = sv;
        float sx = sv, sxx = sv * sv;
        #pragma unroll
        for (int m = 1; m <= 16; m <<= 1) { sx += __shfl_xor(sx, m); sxx += __shfl_xor(sxx, m); }
        float mean = sx * (1.0f / 32.0f);
        float var  = sxx * (1.0f / 32.0f) - mean * mean;
        a_sh[s128][d128] = (sv - mean) * rsqrtf(var + 1e-5f) * lns_g[d128] + lns_b[d128];
    }
    __syncthreads();
    if (tid < 128) {
        float q = 0.f;
        #pragma unroll 8
        for (int j = 0; j < 32; ++j) q = fmaf(Wq[d128 * 32 + j], a_sh[s128][j], q);
        b_sh[s128][d128] = q;
    }
    __syncthreads();
    if (tid < 128) {
        float qv = 0.f;
        #pragma unroll 8
        for (int i = 0; i < 32; ++i) qv = fmaf(b_sh[s128][i], Wk[i * 32 + d128], qv);
        qt_sh[s128][d128] = qv * SCALE;
    }
    __syncthreads();

    const int sub = tid & 3, col0 = sub * 8;
    const int rg  = tid >> 2;
    float g_r[8], e_r[8];
    #pragma unroll
    for (int k = 0; k < 8; ++k) { g_r[k] = lnx_g[col0 + k]; e_r[k] = lnx_b[col0 + k]; }
    const float* xb = x + (size_t)b * Nn * Dn;
    float sv_reg = 0.f;

    for (int it = 0; it < 3; ++it) {
        float qt_r[4][8];
        #pragma unroll
        for (int s = 0; s < 4; ++s)
            #pragma unroll
            for (int k = 0; k < 8; ++k) qt_r[s][k] = qt_sh[s][col0 + k];
        float pu[4][8];
        float ps[4] = {0.f, 0.f, 0.f, 0.f};
        #pragma unroll
        for (int s = 0; s < 4; ++s)
            #pragma unroll
            for (int k = 0; k < 8; ++k) pu[s][k] = 0.f;

        const float* xr0 = xb + (size_t)rg * Dn + col0;
        float4 v0 = *(const float4*)(xr0);
        float4 v1 = *(const float4*)(xr0 + 4);
        #pragma unroll 2
        for (int t = 0; t < STEPS; ++t) {
            const float* xrn = xb + (size_t)((((t + 1) & (STEPS - 1)) * RPS) + rg) * Dn + col0;
            float4 n0 = *(const float4*)(xrn);
            float4 n1 = *(const float4*)(xrn + 4);
            float xv[8] = {v0.x, v0.y, v0.z, v0.w, v1.x, v1.y, v1.z, v1.w};
            float sx = 0.f, sxx = 0.f;
            #pragma unroll
            for (int k = 0; k < 8; ++k) { sx += xv[k]; sxx = fmaf(xv[k], xv[k], sxx); }
            sx += __shfl_xor(sx, 1); sxx += __shfl_xor(sxx, 1);
            sx += __shfl_xor(sx, 2); sxx += __shfl_xor(sxx, 2);
            float mean = sx * (1.0f / 32.0f);
            float var  = sxx * (1.0f / 32.0f) - mean * mean;
            float rs   = rsqrtf(var + 1e-5f);
            float xn[8];
            #pragma unroll
            for (int k = 0; k < 8; ++k) xn[k] = fmaf((xv[k] - mean) * rs, g_r[k], e_r[k]);
            #pragma unroll
            for (int s = 0; s < 4; ++s) {
                float a = 0.f;
                #pragma unroll
                for (int k = 0; k < 8; ++k) a = fmaf(xn[k], qt_r[s][k], a);
                a += __shfl_xor(a, 1);
                a += __shfl_xor(a, 2);
                float w = __expf(a);
                ps[s] += w;
                #pragma unroll
                for (int k = 0; k < 8; ++k) pu[s][k] = fmaf(w, xn[k], pu[s][k]);
            }
            v0 = n0; v1 = n1;
        }
        #pragma unroll
        for (int m = 4; m <= 32; m <<= 1) {
            #pragma unroll
            for (int s = 0; s < 4; ++s) {
                ps[s] += __shfl_xor(ps[s], m);
                #pragma unroll
                for (int k = 0; k < 8; ++k) pu[s][k] += __shfl_xor(pu[s][k], m);
            }
        }
        {
            const int wv = tid >> 6, lane = tid & 63;
            if (lane < 4) {
                #pragma unroll
                for (int s = 0; s < 4; ++s)
                    #pragma unroll
                    for (int k = 0; k < 8; ++k) ls_u[wv][s][lane * 8 + k] = pu[s][k];
                if (lane == 0) {
                    #pragma unroll
                    for (int s = 0; s < 4; ++s) ls_s[wv][s] = ps[s];
                }
            }
        }
        __syncthreads();
        if (tid < 128) {
            float u = 0.f, ss = 0.f;
            #pragma unroll
            for (int w = 0; w < NW; ++w) { u += ls_u[w][s128][d128]; ss += ls_s[w][s128]; }
            a_sh[s128][d128] = (u / ss) * RENORM;
        }
        __syncthreads();
        if (tid < 128) {
            float upd = 0.f;
            #pragma unroll 8
            for (int j = 0; j < 32; ++j) upd = fmaf(Wv[d128 * 32 + j], a_sh[s128][j], upd);
            b_sh[s128][d128] = upd;
        }
        __syncthreads();
        if (tid < 128) {
            float gi[3], gh[3];
            #pragma unroll
            for (int g3 = 0; g3 < 3; ++g3) {
                const int row = g3 * 32 + d128;
                float a1 = bih[row], a2 = bhh[row];
                #pragma unroll 8
                for (int j = 0; j < 32; ++j) {
                    a1 = fmaf(Wih[row * 32 + j], b_sh[s128][j], a1);
                    a2 = fmaf(Whh[row * 32 + j], slots_sh[s128][j], a2);
                }
                gi[g3] = a1; gh[g3] = a2;
            }
            float r  = sigmoidf_(gi[0] + gh[0]);
            float z  = sigmoidf_(gi[1] + gh[1]);
            float nn = tanhf(gi[2] + r * gh[2]);
            sv_reg = (1.0f - z) * nn + z * slots_sh[s128][d128];
            float sx = sv_reg, sxx = sv_reg * sv_reg;
            #pragma unroll
            for (int m = 1; m <= 16; m <<= 1) { sx += __shfl_xor(sx, m); sxx += __shfl_xor(sxx, m); }
            float mean = sx * (1.0f / 32.0f);
            float var  = sxx * (1.0f / 32.0f) - mean * mean;
            a_sh[s128][d128] = (sv_reg - mean) * rsqrtf(var + 1e-5f) * lnff_g[d128] + lnff_b[d128];
        }
        __syncthreads();
        if (tid < 128) {
            float h = b1v[d128];
            #pragma unroll 8
            for (int j = 0; j < 32; ++j) h = fmaf(W1[d128 * 32 + j], a_sh[s128][j], h);
            h_sh[s128][d128] = fmaxf(h, 0.f);
        }
        __syncthreads();
        if (tid < 128) {
            float o = b2v[d128];
            #pragma unroll 8
            for (int j = 0; j < 32; ++j) o = fmaf(W2[d128 * 32 + j], h_sh[s128][j], o);
            float sfin = sv_reg + o;
            slots_sh[s128][d128] = sfin;
            if (it < 2) {
                float sx = sfin, sxx = sfin * sfin;
                #pragma unroll
                for (int m = 1; m <= 16; m <<= 1) { sx += __shfl_xor(sx, m); sxx += __shfl_xor(sxx, m); }
                float mean = sx * (1.0f / 32.0f);
                float var  = sxx * (1.0f / 32.0f) - mean * mean;
                a_sh[s128][d128] = (sfin - mean) * rsqrtf(var + 1e-5f) * lns_g[d128] + lns_b[d128];
            }
        }
        __syncthreads();
        if (it < 2) {
            if (tid < 128) {
                float q = 0.f;
                #pragma unroll 8
                for (int j = 0; j < 32; ++j) q = fmaf(Wq[d128 * 32 + j], a_sh[s128][j], q);
                b_sh[s128][d128] = q;
            }
            __syncthreads();
            if (tid < 128) {
                float qv = 0.f;
                #pragma unroll 8
                for (int i = 0; i < 32; ++i) qv = fmaf(b_sh[s128][i], Wk[i * 32 + d128], qv);
                qt_sh[s128][d128] = qv * SCALE;
            }
            __syncthreads();
        }
    }
    if (tid < 128)
        out[(size_t)b * 128 + tid] = slots_sh[s128][d128];
}

// ---------------------------------------------------------------------------
extern "C" void kernel_launch(void* const* d_in, const int* in_sizes, int n_in,
                              void* d_out, int out_size, void* d_ws, size_t ws_size,
                              hipStream_t stream)
{
    const float* x      = (const float*)d_in[0];
    const float* noise  = (const float*)d_in[1];
    const float* mu     = (const float*)d_in[2];
    const float* logsig = (const float*)d_in[3];
    const float* Wq     = (const float*)d_in[4];
    const float* Wk     = (const float*)d_in[5];
    const float* Wv     = (const float*)d_in[6];
    const float* Wih    = (const float*)d_in[7];
    const float* Whh    = (const float*)d_in[8];
    const float* bih    = (const float*)d_in[9];
    const float* bhh    = (const float*)d_in[10];
    const float* W1     = (const float*)d_in[11];
    const float* b1v    = (const float*)d_in[12];
    const float* W2     = (const float*)d_in[13];
    const float* b2v    = (const float*)d_in[14];
    const float* lnx_g  = (const float*)d_in[15];
    const float* lnx_b  = (const float*)d_in[16];
    const float* lns_g  = (const float*)d_in[17];
    const float* lns_b  = (const float*)d_in[18];
    const float* lnff_g = (const float*)d_in[19];
    const float* lnff_b = (const float*)d_in[20];
    float* out = (float*)d_out;

    if (ws_size >= WS_REQ) {
        float* wsf    = (float*)d_ws;
        float* slots0 = wsf;
        float* slots1 = slots0 + Bn * Sn * Dn;
        float* slots2 = slots1 + Bn * Sn * Dn;
        float* pa0    = slots2 + Bn * Sn * Dn;
        float* pa1    = pa0 + Bn * Cn * Sn * Dn;
        float* pa2    = pa1 + Bn * Cn * Sn * Dn;
        float* pb0    = pa2 + Bn * Cn * Sn * Dn;
        float* pb1    = pb0 + Bn * Cn * Sn;
        float* pb2    = pb1 + Bn * Cn * Sn;
        float* ps0    = pb2 + Bn * Cn * Sn;
        float* ps1    = ps0 + Bn * Cn * Sn;
        float* ps2    = ps1 + Bn * Cn * Sn;

        pass_k<0><<<dim3(Cn, Bn), PT, 0, stream>>>(x, noise, mu, logsig,
            Wq, Wk, Wv, Wih, Whh, bih, bhh, W1, b1v, W2, b2v,
            lnx_g, lnx_b, lns_g, lns_b, lnff_g, lnff_b,
            nullptr, slots0, nullptr, nullptr, nullptr, pa0, pb0, ps0);
        pass_k<1><<<dim3(Cn, Bn), PT, 0, stream>>>(x, noise, mu, logsig,
            Wq, Wk, Wv, Wih, Whh, bih, bhh, W1, b1v, W2, b2v,
            lnx_g, lnx_b, lns_g, lns_b, lnff_g, lnff_b,
            slots0, slots1, pa0, pb0, ps0, pa1, pb1, ps1);
        pass_k<2><<<dim3(Cn, Bn), PT, 0, stream>>>(x, noise, mu, logsig,
            Wq, Wk, Wv, Wih, Whh, bih, bhh, W1, b1v, W2, b2v,
            lnx_g, lnx_b, lns_g, lns_b, lnff_g, lnff_b,
            slots1, slots2, pa1, pb1, ps1, pa2, pb2, ps2);
        final_k<<<Bn, 128, 0, stream>>>(lnx_g, lnx_b, Wv, Wih, Whh, bih, bhh,
            W1, b1v, W2, b2v, lns_g, lns_b, lnff_g, lnff_b, Wq, Wk,
            slots2, pa2, pb2, ps2, out);
    } else {
        slot_fused<<<Bn, TPB, 0, stream>>>(x, noise, mu, logsig, Wq, Wk, Wv,
                                           Wih, Whh, bih, bhh, W1, b1v, W2, b2v,
                                           lnx_g, lnx_b, lns_g, lns_b, lnff_g, lnff_b,
                                           out);
    }
}